// Round 3
// baseline (145.211 us; speedup 1.0000x reference)
//
#include <hip/hip_runtime.h>

#define T_LEN 16384
#define VAR_EPS 1e-5f

// One block per row, 512 threads. Each block reads its row starting at a
// per-row rotated phase ((row*67)&4095 in float4 units, wraparound via mask)
// so that concurrently-executing blocks spread their instantaneous addresses
// across the full 64 KB row window -> decorrelates HBM channel phase.
__global__ __launch_bounds__(512) void pearson_row_kernel(
    const float* __restrict__ pred, const float* __restrict__ target,
    float* __restrict__ out, float inv_B)
{
    const int row = blockIdx.x;
    const int tid = threadIdx.x;
    const float4* __restrict__ p4 =
        (const float4*)(pred + (size_t)row * T_LEN);
    const float4* __restrict__ t4 =
        (const float4*)(target + (size_t)row * T_LEN);

    const int start4 = (row * 67) & 4095;   // per-row phase rotation

    float sp = 0.f, st = 0.f, spp = 0.f, stt = 0.f, spt = 0.f;

    #pragma unroll
    for (int half = 0; half < 2; ++half) {
        const int base = start4 + tid + half * 2048;
        const int i0 = (base        ) & 4095;
        const int i1 = (base +  512) & 4095;
        const int i2 = (base + 1024) & 4095;
        const int i3 = (base + 1536) & 4095;
        float4 a0 = p4[i0];
        float4 a1 = p4[i1];
        float4 a2 = p4[i2];
        float4 a3 = p4[i3];
        float4 b0 = t4[i0];
        float4 b1 = t4[i1];
        float4 b2 = t4[i2];
        float4 b3 = t4[i3];

        sp  += (a0.x + a0.y + a0.z + a0.w) + (a1.x + a1.y + a1.z + a1.w)
             + (a2.x + a2.y + a2.z + a2.w) + (a3.x + a3.y + a3.z + a3.w);
        st  += (b0.x + b0.y + b0.z + b0.w) + (b1.x + b1.y + b1.z + b1.w)
             + (b2.x + b2.y + b2.z + b2.w) + (b3.x + b3.y + b3.z + b3.w);
        spp += a0.x*a0.x + a0.y*a0.y + a0.z*a0.z + a0.w*a0.w
             + a1.x*a1.x + a1.y*a1.y + a1.z*a1.z + a1.w*a1.w
             + a2.x*a2.x + a2.y*a2.y + a2.z*a2.z + a2.w*a2.w
             + a3.x*a3.x + a3.y*a3.y + a3.z*a3.z + a3.w*a3.w;
        stt += b0.x*b0.x + b0.y*b0.y + b0.z*b0.z + b0.w*b0.w
             + b1.x*b1.x + b1.y*b1.y + b1.z*b1.z + b1.w*b1.w
             + b2.x*b2.x + b2.y*b2.y + b2.z*b2.z + b2.w*b2.w
             + b3.x*b3.x + b3.y*b3.y + b3.z*b3.z + b3.w*b3.w;
        spt += a0.x*b0.x + a0.y*b0.y + a0.z*b0.z + a0.w*b0.w
             + a1.x*b1.x + a1.y*b1.y + a1.z*b1.z + a1.w*b1.w
             + a2.x*b2.x + a2.y*b2.y + a2.z*b2.z + a2.w*b2.w
             + a3.x*b3.x + a3.y*b3.y + a3.z*b3.z + a3.w*b3.w;
    }

    // Wave (64-lane) shuffle reduction.
    #pragma unroll
    for (int off = 32; off > 0; off >>= 1) {
        sp  += __shfl_down(sp,  off);
        st  += __shfl_down(st,  off);
        spp += __shfl_down(spp, off);
        stt += __shfl_down(stt, off);
        spt += __shfl_down(spt, off);
    }

    __shared__ float ws[8][5];
    const int lane = tid & 63;
    const int wave = tid >> 6;
    if (lane == 0) {
        ws[wave][0] = sp;  ws[wave][1] = st;  ws[wave][2] = spp;
        ws[wave][3] = stt; ws[wave][4] = spt;
    }
    __syncthreads();

    if (tid == 0) {
        float S_p = 0.f, S_t = 0.f, S_pp = 0.f, S_tt = 0.f, S_pt = 0.f;
        #pragma unroll
        for (int w = 0; w < 8; ++w) {
            S_p  += ws[w][0]; S_t  += ws[w][1]; S_pp += ws[w][2];
            S_tt += ws[w][3]; S_pt += ws[w][4];
        }

        const float T   = (float)T_LEN;
        const float inv = 1.0f / T;
        float cp2 = S_pp - S_p * S_p * inv;
        float ct2 = S_tt - S_t * S_t * inv;
        float num = S_pt - S_p * S_t * inv;

        float var_p = cp2 / (T - 1.0f);
        float var_t = ct2 / (T - 1.0f);
        float denom = sqrtf(cp2 * ct2);
        float safe  = (denom > 0.0f) ? denom : 1.0f;
        float corr  = num / safe;
        bool valid = (var_p > VAR_EPS) && (var_t > VAR_EPS) &&
                     (denom > 0.0f) && !isnan(corr);
        float loss = valid ? (1.0f - corr) : 1.0f;
        atomicAdd(out, loss * inv_B);
    }
}

extern "C" void kernel_launch(void* const* d_in, const int* in_sizes, int n_in,
                              void* d_out, int out_size, void* d_ws, size_t ws_size,
                              hipStream_t stream) {
    const float* pred   = (const float*)d_in[0];
    const float* target = (const float*)d_in[1];
    float* out = (float*)d_out;

    const int B = in_sizes[0] / T_LEN;

    // d_out is poisoned 0xAA before every timed launch -> zero it (capture-safe).
    hipMemsetAsync(out, 0, sizeof(float), stream);
    pearson_row_kernel<<<B, 512, 0, stream>>>(pred, target, out, 1.0f / (float)B);
}

// Round 4
// 144.020 us; speedup vs baseline: 1.0083x; 1.0083x over previous
//
#include <hip/hip_runtime.h>

#define T_LEN 16384
#define Q4    1024          // float4 elements per quarter-row
#define VAR_EPS 1e-5f

// Stage 1: 4 blocks per row (quarter-rows), 256 threads each.
// 4096 blocks -> dispatcher dynamically refills CUs as quarters finish,
// smoothing the L3-hit/HBM-miss row imbalance. Each wave atomicAdds its
// 5 partial moments into moments[row*8 + k].
__global__ __launch_bounds__(256) void pearson_partial_kernel(
    const float* __restrict__ pred, const float* __restrict__ target,
    float* __restrict__ moments)
{
    const int blk = blockIdx.x;
    const int row = blk >> 2;
    const int q   = blk & 3;
    const int tid = threadIdx.x;

    const float4* __restrict__ p4 =
        (const float4*)(pred + (size_t)row * T_LEN) + q * Q4;
    const float4* __restrict__ t4 =
        (const float4*)(target + (size_t)row * T_LEN) + q * Q4;

    // 8 loads issued back-to-back (8 outstanding vmcnt), 16 KB/stream/block.
    float4 a0 = p4[tid];
    float4 a1 = p4[tid + 256];
    float4 a2 = p4[tid + 512];
    float4 a3 = p4[tid + 768];
    float4 b0 = t4[tid];
    float4 b1 = t4[tid + 256];
    float4 b2 = t4[tid + 512];
    float4 b3 = t4[tid + 768];

    float sp  = (a0.x + a0.y + a0.z + a0.w) + (a1.x + a1.y + a1.z + a1.w)
              + (a2.x + a2.y + a2.z + a2.w) + (a3.x + a3.y + a3.z + a3.w);
    float st  = (b0.x + b0.y + b0.z + b0.w) + (b1.x + b1.y + b1.z + b1.w)
              + (b2.x + b2.y + b2.z + b2.w) + (b3.x + b3.y + b3.z + b3.w);
    float spp = a0.x*a0.x + a0.y*a0.y + a0.z*a0.z + a0.w*a0.w
              + a1.x*a1.x + a1.y*a1.y + a1.z*a1.z + a1.w*a1.w
              + a2.x*a2.x + a2.y*a2.y + a2.z*a2.z + a2.w*a2.w
              + a3.x*a3.x + a3.y*a3.y + a3.z*a3.z + a3.w*a3.w;
    float stt = b0.x*b0.x + b0.y*b0.y + b0.z*b0.z + b0.w*b0.w
              + b1.x*b1.x + b1.y*b1.y + b1.z*b1.z + b1.w*b1.w
              + b2.x*b2.x + b2.y*b2.y + b2.z*b2.z + b2.w*b2.w
              + b3.x*b3.x + b3.y*b3.y + b3.z*b3.z + b3.w*b3.w;
    float spt = a0.x*b0.x + a0.y*b0.y + a0.z*b0.z + a0.w*b0.w
              + a1.x*b1.x + a1.y*b1.y + a1.z*b1.z + a1.w*b1.w
              + a2.x*b2.x + a2.y*b2.y + a2.z*b2.z + a2.w*b2.w
              + a3.x*b3.x + a3.y*b3.y + a3.z*b3.z + a3.w*b3.w;

    // 64-lane wave reduction.
    #pragma unroll
    for (int off = 32; off > 0; off >>= 1) {
        sp  += __shfl_down(sp,  off);
        st  += __shfl_down(st,  off);
        spp += __shfl_down(spp, off);
        stt += __shfl_down(stt, off);
        spt += __shfl_down(spt, off);
    }

    if ((tid & 63) == 0) {
        float* m = moments + row * 8;
        atomicAdd(m + 0, sp);
        atomicAdd(m + 1, st);
        atomicAdd(m + 2, spp);
        atomicAdd(m + 3, stt);
        atomicAdd(m + 4, spt);
    }
}

// Stage 2: one block, 1024 threads -> one row each; reduce losses to mean.
__global__ __launch_bounds__(1024) void pearson_final_kernel(
    const float* __restrict__ moments, float* __restrict__ out, int B)
{
    const int tid = threadIdx.x;
    float loss_sum = 0.f;

    for (int r = tid; r < B; r += 1024) {
        const float* m = moments + r * 8;
        float S_p  = m[0];
        float S_t  = m[1];
        float S_pp = m[2];
        float S_tt = m[3];
        float S_pt = m[4];

        const float T   = (float)T_LEN;
        const float inv = 1.0f / T;
        float cp2 = S_pp - S_p * S_p * inv;
        float ct2 = S_tt - S_t * S_t * inv;
        float num = S_pt - S_p * S_t * inv;

        float var_p = cp2 / (T - 1.0f);
        float var_t = ct2 / (T - 1.0f);
        float denom = sqrtf(cp2 * ct2);
        float safe  = (denom > 0.0f) ? denom : 1.0f;
        float corr  = num / safe;
        bool valid = (var_p > VAR_EPS) && (var_t > VAR_EPS) &&
                     (denom > 0.0f) && !isnan(corr);
        loss_sum += valid ? (1.0f - corr) : 1.0f;
    }

    #pragma unroll
    for (int off = 32; off > 0; off >>= 1)
        loss_sum += __shfl_down(loss_sum, off);

    __shared__ float ws[16];
    if ((tid & 63) == 0) ws[tid >> 6] = loss_sum;
    __syncthreads();

    if (tid == 0) {
        float tot = 0.f;
        #pragma unroll
        for (int w = 0; w < 16; ++w) tot += ws[w];
        out[0] = tot / (float)B;
    }
}

extern "C" void kernel_launch(void* const* d_in, const int* in_sizes, int n_in,
                              void* d_out, int out_size, void* d_ws, size_t ws_size,
                              hipStream_t stream) {
    const float* pred   = (const float*)d_in[0];
    const float* target = (const float*)d_in[1];
    float* out     = (float*)d_out;
    float* moments = (float*)d_ws;              // B*8 floats

    const int B = in_sizes[0] / T_LEN;

    // d_ws is poisoned 0xAA before every timed launch -> zero the moments.
    hipMemsetAsync(moments, 0, (size_t)B * 8 * sizeof(float), stream);
    pearson_partial_kernel<<<B * 4, 256, 0, stream>>>(pred, target, moments);
    pearson_final_kernel<<<1, 1024, 0, stream>>>(moments, out, B);
}